// Round 1
// baseline (192.050 us; speedup 1.0000x reference)
//
#include <hip/hip_runtime.h>
#include <math.h>

constexpr int B_ = 8, C_ = 1280, H_ = 7, W_ = 7;
constexpr int M_ = 2048, N_ = 128, HID = 256, NC = 21;
constexpr int PPB = 8;
constexpr int CLS_OFF = 0;
constexpr int DET_OFF = M_ * NC;          // 43008
constexpr int IOU_OFF = M_ * NC + M_ * 4; // 51200

__device__ __forceinline__ float binmax(const float* __restrict__ fp,
                                        int hs, int he, int ws, int we) {
    if (he <= hs || we <= ws) return 0.0f;
    float m = -INFINITY;
    for (int y = hs; y < he; ++y) {
        const float* row = fp + y * W_;
        for (int x = ws; x < we; ++x) m = fmaxf(m, row[x]);
    }
    return m;
}

__global__ __launch_bounds__(256) void frcnn_fused(
    const float* __restrict__ fmap, const float* __restrict__ props,
    const float* __restrict__ bbx,  const float* __restrict__ W1,
    const float* __restrict__ b1v,  const float* __restrict__ W2,
    const float* __restrict__ b2v,  const float* __restrict__ Wc,
    const float* __restrict__ bc,   const float* __restrict__ Wd,
    const float* __restrict__ bd,   const int* __restrict__ pbid,
    const int* __restrict__ gbid,   float* __restrict__ out)
{
    __shared__ __align__(16) float feat[PPB][C_];     // 40 KB
    __shared__ __align__(16) float h1s[PPB][HID];     // 8 KB
    __shared__ float h2s[PPB][HID + 1];               // padded: FC3 reads stride-257
    __shared__ int   bins[PPB][9];
    __shared__ float gbox[N_][4];
    __shared__ int   gids[N_];

    const int tid = threadIdx.x;
    const int m0  = blockIdx.x * PPB;

    // stage gt boxes + ids
    for (int i = tid; i < N_; i += 256) {
        gbox[i][0] = bbx[i * 5 + 0];
        gbox[i][1] = bbx[i * 5 + 1];
        gbox[i][2] = bbx[i * 5 + 2];
        gbox[i][3] = bbx[i * 5 + 3];
        gids[i] = gbid[i];
    }
    // per-proposal quantized bin bounds (torchvision roi_pool semantics)
    if (tid < PPB) {
        int m = m0 + tid;
        float4 bx = *(const float4*)(props + (size_t)m * 4);
        float x1 = rintf(bx.x), y1 = rintf(bx.y);
        float x2 = rintf(bx.z), y2 = rintf(bx.w);
        float rw = fmaxf(x2 - x1 + 1.0f, 1.0f);
        float rh = fmaxf(y2 - y1 + 1.0f, 1.0f);
        float bw = rw * 0.5f, bh = rh * 0.5f;
        float hs0 = fminf(fmaxf(y1, 0.f), 7.f);
        float he0 = fminf(fmaxf(ceilf(bh) + y1, 0.f), 7.f);
        float hs1 = fminf(fmaxf(floorf(bh) + y1, 0.f), 7.f);
        float he1 = fminf(fmaxf(ceilf(2.f * bh) + y1, 0.f), 7.f);
        float ws0 = fminf(fmaxf(x1, 0.f), 7.f);
        float we0 = fminf(fmaxf(ceilf(bw) + x1, 0.f), 7.f);
        float ws1 = fminf(fmaxf(floorf(bw) + x1, 0.f), 7.f);
        float we1 = fminf(fmaxf(ceilf(2.f * bw) + x1, 0.f), 7.f);
        bins[tid][0] = (int)hs0; bins[tid][1] = (int)he0;
        bins[tid][2] = (int)hs1; bins[tid][3] = (int)he1;
        bins[tid][4] = (int)ws0; bins[tid][5] = (int)we0;
        bins[tid][6] = (int)ws1; bins[tid][7] = (int)we1;
        bins[tid][8] = pbid[m];
    }
    __syncthreads();

    // ROI max-pool 2x2 + mean -> feat[p][c]
    for (int c = tid; c < C_; c += 256) {
        #pragma unroll
        for (int p = 0; p < PPB; ++p) {
            const int* bn = bins[p];
            const float* fp = fmap + (size_t)(bn[8] * C_ + c) * (H_ * W_);
            float s = binmax(fp, bn[0], bn[1], bn[4], bn[5])
                    + binmax(fp, bn[0], bn[1], bn[6], bn[7])
                    + binmax(fp, bn[2], bn[3], bn[4], bn[5])
                    + binmax(fp, bn[2], bn[3], bn[6], bn[7]);
            feat[p][c] = s * 0.25f;
        }
    }
    __syncthreads();

    // FC1 + ReLU: h1 = relu(feat @ W1 + b1)   (1280 -> 256)
    {
        float acc[PPB];
        float bias = b1v[tid];
        #pragma unroll
        for (int p = 0; p < PPB; ++p) acc[p] = bias;
        for (int k = 0; k < C_; k += 4) {
            float w0 = W1[(k + 0) * HID + tid];
            float w1 = W1[(k + 1) * HID + tid];
            float w2 = W1[(k + 2) * HID + tid];
            float w3 = W1[(k + 3) * HID + tid];
            #pragma unroll
            for (int p = 0; p < PPB; ++p) {
                float4 f = *(const float4*)&feat[p][k];
                acc[p] = fmaf(f.w, w3, fmaf(f.z, w2, fmaf(f.y, w1, fmaf(f.x, w0, acc[p]))));
            }
        }
        #pragma unroll
        for (int p = 0; p < PPB; ++p) h1s[p][tid] = fmaxf(acc[p], 0.0f);
    }
    __syncthreads();

    // FC2 (no relu): h2 = h1 @ W2 + b2   (256 -> 256)
    {
        float acc[PPB];
        float bias = b2v[tid];
        #pragma unroll
        for (int p = 0; p < PPB; ++p) acc[p] = bias;
        for (int k = 0; k < HID; k += 4) {
            float w0 = W2[(k + 0) * HID + tid];
            float w1 = W2[(k + 1) * HID + tid];
            float w2 = W2[(k + 2) * HID + tid];
            float w3 = W2[(k + 3) * HID + tid];
            #pragma unroll
            for (int p = 0; p < PPB; ++p) {
                float4 f = *(const float4*)&h1s[p][k];
                acc[p] = fmaf(f.w, w3, fmaf(f.z, w2, fmaf(f.y, w1, fmaf(f.x, w0, acc[p]))));
            }
        }
        #pragma unroll
        for (int p = 0; p < PPB; ++p) h2s[p][tid] = acc[p];
    }
    __syncthreads();

    // heads: cls (21) + det (4) per proposal; 32 lanes per proposal, 25 active
    {
        int p = tid >> 5, oo = tid & 31;
        if (oo < NC + 4) {
            const float* wp; int str; float bias; float* op;
            if (oo < NC) {
                wp = Wc + oo; str = NC; bias = bc[oo];
                op = out + CLS_OFF + (size_t)(m0 + p) * NC + oo;
            } else {
                int o = oo - NC;
                wp = Wd + o; str = 4; bias = bd[o];
                op = out + DET_OFF + (size_t)(m0 + p) * 4 + o;
            }
            float s = bias;
            for (int k = 0; k < HID; ++k) s = fmaf(h2s[p][k], wp[k * str], s);
            *op = s;
        }
    }

    // max IoU vs same-image gt boxes (unrounded proposals)
    {
        int p = tid >> 5, l = tid & 31;
        int m = m0 + p;
        float4 bx = *(const float4*)(props + (size_t)m * 4);
        float ap = (bx.z - bx.x) * (bx.w - bx.y);
        int pb = bins[p][8];
        float best = 0.0f;
        for (int n = l; n < N_; n += 32) {
            if (gids[n] == pb) {
                float gx1 = gbox[n][0], gy1 = gbox[n][1];
                float gx2 = gbox[n][2], gy2 = gbox[n][3];
                float ix = fmaxf(fminf(bx.z, gx2) - fmaxf(bx.x, gx1), 0.0f);
                float iy = fmaxf(fminf(bx.w, gy2) - fmaxf(bx.y, gy1), 0.0f);
                float inter = ix * iy;
                float ag = (gx2 - gx1) * (gy2 - gy1);
                float un = fmaxf(ap + ag - inter, 1e-6f);
                best = fmaxf(best, inter / un);
            }
        }
        #pragma unroll
        for (int off = 16; off; off >>= 1)
            best = fmaxf(best, __shfl_xor(best, off));
        if (l == 0) out[IOU_OFF + m] = best;
    }
}

extern "C" void kernel_launch(void* const* d_in, const int* in_sizes, int n_in,
                              void* d_out, int out_size, void* d_ws, size_t ws_size,
                              hipStream_t stream) {
    const float* fmap  = (const float*)d_in[0];
    const float* props = (const float*)d_in[1];
    const float* bbx   = (const float*)d_in[2];
    const float* W1    = (const float*)d_in[3];
    const float* b1v   = (const float*)d_in[4];
    const float* W2    = (const float*)d_in[5];
    const float* b2v   = (const float*)d_in[6];
    const float* Wc    = (const float*)d_in[7];
    const float* bc    = (const float*)d_in[8];
    const float* Wd    = (const float*)d_in[9];
    const float* bd    = (const float*)d_in[10];
    const int*   pbid  = (const int*)d_in[11];
    const int*   gbid  = (const int*)d_in[12];
    float* out = (float*)d_out;

    frcnn_fused<<<dim3(M_ / PPB), dim3(256), 0, stream>>>(
        fmap, props, bbx, W1, b1v, W2, b2v, Wc, bc, Wd, bd, pbid, gbid, out);
}

// Round 2
// 180.888 us; speedup vs baseline: 1.0617x; 1.0617x over previous
//
#include <hip/hip_runtime.h>
#include <math.h>

constexpr int B_ = 8, C_ = 1280, H_ = 7, W_ = 7;
constexpr int M_ = 2048, N_ = 128, HID = 256, NC = 21;
constexpr int DET_OFF = M_ * NC;          // 43008
constexpr int IOU_OFF = M_ * NC + M_ * 4; // 51200

typedef __attribute__((ext_vector_type(8))) short bf16x8;
typedef __attribute__((ext_vector_type(4))) float f32x4;

// ws layout (bytes)
constexpr size_t FEATB_OFF = 0;                               // 2048*1280*2 = 5242880
constexpr size_t W1T_OFF   = 5242880;                         // 1280*256*2  =  655360
constexpr size_t W2T_OFF   = W1T_OFF + 655360;                // 256*256*2   =  131072
constexpr size_t WHT_OFF   = W2T_OFF + 131072;                // 32*256*2    =   16384

__device__ __forceinline__ unsigned short f2bf(float f) {
    unsigned u = __builtin_bit_cast(unsigned, f);
    u += 0x7FFFu + ((u >> 16) & 1u);   // round-to-nearest-even
    return (unsigned short)(u >> 16);
}

__device__ __forceinline__ float binmax(const float* __restrict__ fp,
                                        int hs, int he, int ws, int we) {
    if (he <= hs || we <= ws) return 0.0f;
    float m = -INFINITY;
    for (int y = hs; y < he; ++y) {
        const float* row = fp + y * W_;
        for (int x = ws; x < we; ++x) m = fmaxf(m, row[x]);
    }
    return m;
}

// ---------- prep: W1^T, W2^T, Whead^T (padded to 32 cols) in bf16 ----------
__global__ __launch_bounds__(256) void k_prep(
    const float* __restrict__ W1, const float* __restrict__ W2,
    const float* __restrict__ Wc, const float* __restrict__ Wd,
    unsigned short* __restrict__ W1t, unsigned short* __restrict__ W2t,
    unsigned short* __restrict__ Wht)
{
    int idx = blockIdx.x * 256 + threadIdx.x;
    if (idx < C_ * HID) {
        int col = idx & 255, k = idx >> 8;
        W1t[col * C_ + k] = f2bf(W1[k * HID + col]);
    } else if (idx < C_ * HID + HID * HID) {
        int i = idx - C_ * HID;
        int col = i & 255, k = i >> 8;
        W2t[col * HID + k] = f2bf(W2[k * HID + col]);
    } else {
        int i = idx - C_ * HID - HID * HID;
        if (i < 32 * HID) {
            int o = i & 31, k = i >> 5;
            float v = 0.0f;
            if (o < NC) v = Wc[k * NC + o];
            else if (o < NC + 4) v = Wd[k * 4 + (o - NC)];
            Wht[o * HID + k] = f2bf(v);
        }
    }
}

// ---------- ROI pool: one wave per proposal, lanes = channels ----------
__global__ __launch_bounds__(256) void k_roi(
    const float* __restrict__ fmap, const float* __restrict__ props,
    const int* __restrict__ pbid, unsigned short* __restrict__ featb)
{
    int m = (blockIdx.x << 2) + (threadIdx.x >> 6);
    int lane = threadIdx.x & 63;

    float4 bx = *(const float4*)(props + (size_t)m * 4);
    float x1 = rintf(bx.x), y1 = rintf(bx.y);
    float x2 = rintf(bx.z), y2 = rintf(bx.w);
    float rw = fmaxf(x2 - x1 + 1.0f, 1.0f);
    float rh = fmaxf(y2 - y1 + 1.0f, 1.0f);
    float bw = rw * 0.5f, bh = rh * 0.5f;
    int hs0 = (int)fminf(fmaxf(y1, 0.f), 7.f);
    int he0 = (int)fminf(fmaxf(ceilf(bh) + y1, 0.f), 7.f);
    int hs1 = (int)fminf(fmaxf(floorf(bh) + y1, 0.f), 7.f);
    int he1 = (int)fminf(fmaxf(ceilf(2.f * bh) + y1, 0.f), 7.f);
    int ws0 = (int)fminf(fmaxf(x1, 0.f), 7.f);
    int we0 = (int)fminf(fmaxf(ceilf(bw) + x1, 0.f), 7.f);
    int ws1 = (int)fminf(fmaxf(floorf(bw) + x1, 0.f), 7.f);
    int we1 = (int)fminf(fmaxf(ceilf(2.f * bw) + x1, 0.f), 7.f);
    int bid = pbid[m];

    const float* base = fmap + (size_t)bid * C_ * (H_ * W_);
    for (int c = lane; c < C_; c += 64) {
        const float* fp = base + c * (H_ * W_);
        float s = binmax(fp, hs0, he0, ws0, we0)
                + binmax(fp, hs0, he0, ws1, we1)
                + binmax(fp, hs1, he1, ws0, we0)
                + binmax(fp, hs1, he1, ws1, we1);
        featb[(size_t)m * C_ + c] = f2bf(s * 0.25f);
    }
}

// ---------- fused FC1 -> FC2 -> heads + IoU ----------
__global__ __launch_bounds__(256) void k_fc(
    const unsigned short* __restrict__ featb,
    const unsigned short* __restrict__ W1t,
    const unsigned short* __restrict__ W2t,
    const unsigned short* __restrict__ Wht,
    const float* __restrict__ b1v, const float* __restrict__ b2v,
    const float* __restrict__ bc,  const float* __restrict__ bd,
    const float* __restrict__ props, const int* __restrict__ pbid,
    const float* __restrict__ bbx,   const int* __restrict__ gbid,
    float* __restrict__ out)
{
    __shared__ unsigned short h1s[16][264];  // pitch 264 bf16 = 528 B (16B aligned)
    __shared__ unsigned short h2s[16][264];
    __shared__ float gbox[N_][4];
    __shared__ int   gids[N_];

    const int tid = threadIdx.x;
    const int w = tid >> 6, lane = tid & 63;
    const int r = lane & 15, g = lane >> 4;
    const int row0 = blockIdx.x * 16;
    const int col0 = w * 64;

    for (int i = tid; i < N_; i += 256) {
        gbox[i][0] = bbx[i * 5 + 0];
        gbox[i][1] = bbx[i * 5 + 1];
        gbox[i][2] = bbx[i * 5 + 2];
        gbox[i][3] = bbx[i * 5 + 3];
        gids[i] = gbid[i];
    }

    // ---- FC1: (16 x 1280) @ (1280 x 256), wave covers 64 cols ----
    f32x4 acc[4];
    #pragma unroll
    for (int f = 0; f < 4; ++f) acc[f] = (f32x4){0.f, 0.f, 0.f, 0.f};

    const unsigned short* ap = featb + (size_t)(row0 + r) * C_ + g * 8;
    const unsigned short* bp = W1t + (size_t)(col0 + r) * C_ + g * 8;
    for (int ks = 0; ks < C_ / 32; ++ks) {
        bf16x8 a = *(const bf16x8*)(ap + ks * 32);
        #pragma unroll
        for (int f = 0; f < 4; ++f) {
            bf16x8 b = *(const bf16x8*)(bp + (size_t)f * 16 * C_ + ks * 32);
            acc[f] = __builtin_amdgcn_mfma_f32_16x16x32_bf16(a, b, acc[f], 0, 0, 0);
        }
    }
    #pragma unroll
    for (int f = 0; f < 4; ++f) {
        int col = col0 + f * 16 + r;
        float bias = b1v[col];
        #pragma unroll
        for (int i = 0; i < 4; ++i)
            h1s[g * 4 + i][col] = f2bf(fmaxf(acc[f][i] + bias, 0.f));
    }
    __syncthreads();

    // ---- FC2: (16 x 256) @ (256 x 256), A from LDS ----
    f32x4 acc2[4];
    #pragma unroll
    for (int f = 0; f < 4; ++f) acc2[f] = (f32x4){0.f, 0.f, 0.f, 0.f};

    const unsigned short* bp2 = W2t + (size_t)(col0 + r) * HID + g * 8;
    for (int ks = 0; ks < HID / 32; ++ks) {
        bf16x8 a = *(const bf16x8*)(&h1s[r][ks * 32 + g * 8]);
        #pragma unroll
        for (int f = 0; f < 4; ++f) {
            bf16x8 b = *(const bf16x8*)(bp2 + (size_t)f * 16 * HID + ks * 32);
            acc2[f] = __builtin_amdgcn_mfma_f32_16x16x32_bf16(a, b, acc2[f], 0, 0, 0);
        }
    }
    #pragma unroll
    for (int f = 0; f < 4; ++f) {
        int col = col0 + f * 16 + r;
        float bias = b2v[col];
        #pragma unroll
        for (int i = 0; i < 4; ++i)
            h2s[g * 4 + i][col] = f2bf(acc2[f][i] + bias);
    }
    __syncthreads();

    // ---- heads on wave 0: (16 x 256) @ (256 x 32[25 valid]) ----
    if (w == 0) {
        f32x4 acc3[2];
        #pragma unroll
        for (int f = 0; f < 2; ++f) acc3[f] = (f32x4){0.f, 0.f, 0.f, 0.f};
        const unsigned short* bp3 = Wht + (size_t)r * HID + g * 8;
        for (int ks = 0; ks < HID / 32; ++ks) {
            bf16x8 a = *(const bf16x8*)(&h2s[r][ks * 32 + g * 8]);
            #pragma unroll
            for (int f = 0; f < 2; ++f) {
                bf16x8 b = *(const bf16x8*)(bp3 + (size_t)f * 16 * HID + ks * 32);
                acc3[f] = __builtin_amdgcn_mfma_f32_16x16x32_bf16(a, b, acc3[f], 0, 0, 0);
            }
        }
        #pragma unroll
        for (int f = 0; f < 2; ++f) {
            int col = f * 16 + r;
            #pragma unroll
            for (int i = 0; i < 4; ++i) {
                int m = row0 + g * 4 + i;
                if (col < NC)
                    out[(size_t)m * NC + col] = acc3[f][i] + bc[col];
                else if (col < NC + 4)
                    out[DET_OFF + (size_t)m * 4 + (col - NC)] = acc3[f][i] + bd[col - NC];
            }
        }
    }

    // ---- IoU: 16 threads per proposal ----
    {
        int rr = tid >> 4, l4 = tid & 15;
        int m = row0 + rr;
        float4 bx = *(const float4*)(props + (size_t)m * 4);
        float ap2 = (bx.z - bx.x) * (bx.w - bx.y);
        int pb = pbid[m];
        float best = 0.0f;
        for (int n = l4; n < N_; n += 16) {
            if (gids[n] == pb) {
                float ix = fmaxf(fminf(bx.z, gbox[n][2]) - fmaxf(bx.x, gbox[n][0]), 0.0f);
                float iy = fmaxf(fminf(bx.w, gbox[n][3]) - fmaxf(bx.y, gbox[n][1]), 0.0f);
                float inter = ix * iy;
                float ag = (gbox[n][2] - gbox[n][0]) * (gbox[n][3] - gbox[n][1]);
                float un = fmaxf(ap2 + ag - inter, 1e-6f);
                best = fmaxf(best, inter / un);
            }
        }
        #pragma unroll
        for (int off = 8; off; off >>= 1)
            best = fmaxf(best, __shfl_xor(best, off));
        if (l4 == 0) out[IOU_OFF + m] = best;
    }
}

extern "C" void kernel_launch(void* const* d_in, const int* in_sizes, int n_in,
                              void* d_out, int out_size, void* d_ws, size_t ws_size,
                              hipStream_t stream) {
    const float* fmap  = (const float*)d_in[0];
    const float* props = (const float*)d_in[1];
    const float* bbx   = (const float*)d_in[2];
    const float* W1    = (const float*)d_in[3];
    const float* b1v   = (const float*)d_in[4];
    const float* W2    = (const float*)d_in[5];
    const float* b2v   = (const float*)d_in[6];
    const float* Wc    = (const float*)d_in[7];
    const float* bc    = (const float*)d_in[8];
    const float* Wd    = (const float*)d_in[9];
    const float* bd    = (const float*)d_in[10];
    const int*   pbid  = (const int*)d_in[11];
    const int*   gbid  = (const int*)d_in[12];
    float* out = (float*)d_out;

    char* ws = (char*)d_ws;
    unsigned short* featb = (unsigned short*)(ws + FEATB_OFF);
    unsigned short* W1t   = (unsigned short*)(ws + W1T_OFF);
    unsigned short* W2t   = (unsigned short*)(ws + W2T_OFF);
    unsigned short* Wht   = (unsigned short*)(ws + WHT_OFF);

    k_prep<<<dim3((C_ * HID + HID * HID + 32 * HID + 255) / 256), dim3(256), 0, stream>>>(
        W1, W2, Wc, Wd, W1t, W2t, Wht);
    k_roi<<<dim3(M_ / 4), dim3(256), 0, stream>>>(fmap, props, pbid, featb);
    k_fc<<<dim3(M_ / 16), dim3(256), 0, stream>>>(
        featb, W1t, W2t, Wht, b1v, b2v, bc, bd, props, pbid, bbx, gbid, out);
}

// Round 3
// 65.282 us; speedup vs baseline: 2.9419x; 2.7709x over previous
//
#include <hip/hip_runtime.h>
#include <math.h>

constexpr int B_ = 8, C_ = 1280, H_ = 7, W_ = 7;
constexpr int M_ = 2048, N_ = 128, HID = 256, NC = 21;
constexpr int DET_OFF = M_ * NC;          // 43008
constexpr int IOU_OFF = M_ * NC + M_ * 4; // 51200

typedef __attribute__((ext_vector_type(8))) short bf16x8;
typedef __attribute__((ext_vector_type(4))) float f32x4;

// ws layout (bytes)
constexpr size_t FEATB_OFF = 0;                               // 2048*1280*2 = 5242880
constexpr size_t W1T_OFF   = 5242880;                         // 1280*256*2  =  655360
constexpr size_t W2T_OFF   = W1T_OFF + 655360;                // 256*256*2   =  131072
constexpr size_t WHT_OFF   = W2T_OFF + 131072;                // 32*256*2    =   16384
constexpr size_t FMT_OFF   = WHT_OFF + 16384;                 // 8*49*1280*4 = 2007040
// total ~8.05 MB

__device__ __forceinline__ unsigned short f2bf(float f) {
    unsigned u = __builtin_bit_cast(unsigned, f);
    u += 0x7FFFu + ((u >> 16) & 1u);   // round-to-nearest-even
    return (unsigned short)(u >> 16);
}

__device__ __forceinline__ float4 max4(float4 a, float4 b) {
    return make_float4(fmaxf(a.x, b.x), fmaxf(a.y, b.y),
                       fmaxf(a.z, b.z), fmaxf(a.w, b.w));
}

// ---------- prep: W1^T, W2^T, Whead^T (padded to 32 cols) in bf16 ----------
__global__ __launch_bounds__(256) void k_prep(
    const float* __restrict__ W1, const float* __restrict__ W2,
    const float* __restrict__ Wc, const float* __restrict__ Wd,
    unsigned short* __restrict__ W1t, unsigned short* __restrict__ W2t,
    unsigned short* __restrict__ Wht)
{
    int idx = blockIdx.x * 256 + threadIdx.x;
    if (idx < C_ * HID) {
        int col = idx & 255, k = idx >> 8;
        W1t[col * C_ + k] = f2bf(W1[k * HID + col]);
    } else if (idx < C_ * HID + HID * HID) {
        int i = idx - C_ * HID;
        int col = i & 255, k = i >> 8;
        W2t[col * HID + k] = f2bf(W2[k * HID + col]);
    } else {
        int i = idx - C_ * HID - HID * HID;
        if (i < 32 * HID) {
            int o = i & 31, k = i >> 5;
            float v = 0.0f;
            if (o < NC) v = Wc[k * NC + o];
            else if (o < NC + 4) v = Wd[k * 4 + (o - NC)];
            Wht[o * HID + k] = f2bf(v);
        }
    }
}

// ---------- transpose fmap: [B][C][49] -> [B][49][C] ----------
__global__ __launch_bounds__(256) void k_tr(
    const float* __restrict__ fmap, float* __restrict__ fmt)
{
    int idx = blockIdx.x * 256 + threadIdx.x;   // total 8*49*1280 = 501760
    int c   = idx % C_;
    int t   = idx / C_;
    int pix = t % 49;
    int img = t / 49;
    fmt[idx] = fmap[((size_t)img * C_ + c) * 49 + pix];
}

// ---------- ROI pool from transposed map: wave = (proposal, 256-ch slab) ----------
__global__ __launch_bounds__(256) void k_pool(
    const float* __restrict__ fmt, const float* __restrict__ props,
    const int* __restrict__ pbid, unsigned short* __restrict__ featb)
{
    int wg   = blockIdx.x * 4 + (threadIdx.x >> 6);   // 10240 waves
    int lane = threadIdx.x & 63;
    int m    = wg / 5;
    int slab = wg - m * 5;
    int c0   = slab * 256 + lane * 4;

    float4 bx = *(const float4*)(props + (size_t)m * 4);
    float x1 = rintf(bx.x), y1 = rintf(bx.y);
    float x2 = rintf(bx.z), y2 = rintf(bx.w);
    float rw = fmaxf(x2 - x1 + 1.0f, 1.0f);
    float rh = fmaxf(y2 - y1 + 1.0f, 1.0f);
    float bw = rw * 0.5f, bh = rh * 0.5f;
    int hs0 = (int)fminf(fmaxf(y1, 0.f), 7.f);
    int he0 = (int)fminf(fmaxf(ceilf(bh) + y1, 0.f), 7.f);
    int hs1 = (int)fminf(fmaxf(floorf(bh) + y1, 0.f), 7.f);
    int he1 = (int)fminf(fmaxf(ceilf(2.f * bh) + y1, 0.f), 7.f);
    int ws0 = (int)fminf(fmaxf(x1, 0.f), 7.f);
    int we0 = (int)fminf(fmaxf(ceilf(bw) + x1, 0.f), 7.f);
    int ws1 = (int)fminf(fmaxf(floorf(bw) + x1, 0.f), 7.f);
    int we1 = (int)fminf(fmaxf(ceilf(2.f * bw) + x1, 0.f), 7.f);
    int bid  = pbid[m];

    const float* base = fmt + ((size_t)bid * 49) * C_ + c0;
    const float4 ninf = make_float4(-INFINITY, -INFINITY, -INFINITY, -INFINITY);
    float4 b00 = ninf, b01 = ninf, b10 = ninf, b11 = ninf;

    for (int y = hs0; y < he1; ++y) {
        float4 r0 = ninf, r1 = ninf;
        const float* rowp = base + (y * 7) * C_;
        for (int x = ws0; x < we1; ++x) {
            float4 v = *(const float4*)(rowp + x * C_);
            if (x < we0)               r0 = max4(r0, v);   // x>=ws0 implicit
            if (x >= ws1)              r1 = max4(r1, v);   // x<we1 implicit
        }
        if (y < he0)  { b00 = max4(b00, r0); b01 = max4(b01, r1); }  // y>=hs0 implicit
        if (y >= hs1) { b10 = max4(b10, r0); b11 = max4(b11, r1); }  // y<he1 implicit
    }

    bool e00 = (he0 <= hs0) | (we0 <= ws0);
    bool e01 = (he0 <= hs0) | (we1 <= ws1);
    bool e10 = (he1 <= hs1) | (we0 <= ws0);
    bool e11 = (he1 <= hs1) | (we1 <= ws1);
    float4 z = make_float4(0.f, 0.f, 0.f, 0.f);
    float4 f00 = e00 ? z : b00;
    float4 f01 = e01 ? z : b01;
    float4 f10 = e10 ? z : b10;
    float4 f11 = e11 ? z : b11;

    ushort4 o;
    o.x = f2bf((f00.x + f01.x + f10.x + f11.x) * 0.25f);
    o.y = f2bf((f00.y + f01.y + f10.y + f11.y) * 0.25f);
    o.z = f2bf((f00.z + f01.z + f10.z + f11.z) * 0.25f);
    o.w = f2bf((f00.w + f01.w + f10.w + f11.w) * 0.25f);
    *(ushort4*)(featb + (size_t)m * C_ + c0) = o;
}

// ---------- fused FC1 -> FC2 -> heads + IoU ----------
__global__ __launch_bounds__(256) void k_fc(
    const unsigned short* __restrict__ featb,
    const unsigned short* __restrict__ W1t,
    const unsigned short* __restrict__ W2t,
    const unsigned short* __restrict__ Wht,
    const float* __restrict__ b1v, const float* __restrict__ b2v,
    const float* __restrict__ bc,  const float* __restrict__ bd,
    const float* __restrict__ props, const int* __restrict__ pbid,
    const float* __restrict__ bbx,   const int* __restrict__ gbid,
    float* __restrict__ out)
{
    __shared__ unsigned short h1s[16][264];
    __shared__ unsigned short h2s[16][264];
    __shared__ float gbox[N_][4];
    __shared__ int   gids[N_];

    const int tid = threadIdx.x;
    const int w = tid >> 6, lane = tid & 63;
    const int r = lane & 15, g = lane >> 4;
    const int row0 = blockIdx.x * 16;
    const int col0 = w * 64;

    for (int i = tid; i < N_; i += 256) {
        gbox[i][0] = bbx[i * 5 + 0];
        gbox[i][1] = bbx[i * 5 + 1];
        gbox[i][2] = bbx[i * 5 + 2];
        gbox[i][3] = bbx[i * 5 + 3];
        gids[i] = gbid[i];
    }

    // ---- FC1 ----
    f32x4 acc[4];
    #pragma unroll
    for (int f = 0; f < 4; ++f) acc[f] = (f32x4){0.f, 0.f, 0.f, 0.f};

    const unsigned short* ap = featb + (size_t)(row0 + r) * C_ + g * 8;
    const unsigned short* bp = W1t + (size_t)(col0 + r) * C_ + g * 8;
    for (int ks = 0; ks < C_ / 32; ++ks) {
        bf16x8 a = *(const bf16x8*)(ap + ks * 32);
        #pragma unroll
        for (int f = 0; f < 4; ++f) {
            bf16x8 b = *(const bf16x8*)(bp + (size_t)f * 16 * C_ + ks * 32);
            acc[f] = __builtin_amdgcn_mfma_f32_16x16x32_bf16(a, b, acc[f], 0, 0, 0);
        }
    }
    #pragma unroll
    for (int f = 0; f < 4; ++f) {
        int col = col0 + f * 16 + r;
        float bias = b1v[col];
        #pragma unroll
        for (int i = 0; i < 4; ++i)
            h1s[g * 4 + i][col] = f2bf(fmaxf(acc[f][i] + bias, 0.f));
    }
    __syncthreads();

    // ---- FC2 ----
    f32x4 acc2[4];
    #pragma unroll
    for (int f = 0; f < 4; ++f) acc2[f] = (f32x4){0.f, 0.f, 0.f, 0.f};

    const unsigned short* bp2 = W2t + (size_t)(col0 + r) * HID + g * 8;
    for (int ks = 0; ks < HID / 32; ++ks) {
        bf16x8 a = *(const bf16x8*)(&h1s[r][ks * 32 + g * 8]);
        #pragma unroll
        for (int f = 0; f < 4; ++f) {
            bf16x8 b = *(const bf16x8*)(bp2 + (size_t)f * 16 * HID + ks * 32);
            acc2[f] = __builtin_amdgcn_mfma_f32_16x16x32_bf16(a, b, acc2[f], 0, 0, 0);
        }
    }
    #pragma unroll
    for (int f = 0; f < 4; ++f) {
        int col = col0 + f * 16 + r;
        float bias = b2v[col];
        #pragma unroll
        for (int i = 0; i < 4; ++i)
            h2s[g * 4 + i][col] = f2bf(acc2[f][i] + bias);
    }
    __syncthreads();

    // ---- heads on wave 0 ----
    if (w == 0) {
        f32x4 acc3[2];
        #pragma unroll
        for (int f = 0; f < 2; ++f) acc3[f] = (f32x4){0.f, 0.f, 0.f, 0.f};
        const unsigned short* bp3 = Wht + (size_t)r * HID + g * 8;
        for (int ks = 0; ks < HID / 32; ++ks) {
            bf16x8 a = *(const bf16x8*)(&h2s[r][ks * 32 + g * 8]);
            #pragma unroll
            for (int f = 0; f < 2; ++f) {
                bf16x8 b = *(const bf16x8*)(bp3 + (size_t)f * 16 * HID + ks * 32);
                acc3[f] = __builtin_amdgcn_mfma_f32_16x16x32_bf16(a, b, acc3[f], 0, 0, 0);
            }
        }
        #pragma unroll
        for (int f = 0; f < 2; ++f) {
            int col = f * 16 + r;
            #pragma unroll
            for (int i = 0; i < 4; ++i) {
                int m = row0 + g * 4 + i;
                if (col < NC)
                    out[(size_t)m * NC + col] = acc3[f][i] + bc[col];
                else if (col < NC + 4)
                    out[DET_OFF + (size_t)m * 4 + (col - NC)] = acc3[f][i] + bd[col - NC];
            }
        }
    }

    // ---- IoU: 16 threads per proposal ----
    {
        int rr = tid >> 4, l4 = tid & 15;
        int m = row0 + rr;
        float4 bx = *(const float4*)(props + (size_t)m * 4);
        float ap2 = (bx.z - bx.x) * (bx.w - bx.y);
        int pb = pbid[m];
        float best = 0.0f;
        for (int n = l4; n < N_; n += 16) {
            if (gids[n] == pb) {
                float ix = fmaxf(fminf(bx.z, gbox[n][2]) - fmaxf(bx.x, gbox[n][0]), 0.0f);
                float iy = fmaxf(fminf(bx.w, gbox[n][3]) - fmaxf(bx.y, gbox[n][1]), 0.0f);
                float inter = ix * iy;
                float ag = (gbox[n][2] - gbox[n][0]) * (gbox[n][3] - gbox[n][1]);
                float un = fmaxf(ap2 + ag - inter, 1e-6f);
                best = fmaxf(best, inter / un);
            }
        }
        #pragma unroll
        for (int off = 8; off; off >>= 1)
            best = fmaxf(best, __shfl_xor(best, off));
        if (l4 == 0) out[IOU_OFF + m] = best;
    }
}

extern "C" void kernel_launch(void* const* d_in, const int* in_sizes, int n_in,
                              void* d_out, int out_size, void* d_ws, size_t ws_size,
                              hipStream_t stream) {
    const float* fmap  = (const float*)d_in[0];
    const float* props = (const float*)d_in[1];
    const float* bbx   = (const float*)d_in[2];
    const float* W1    = (const float*)d_in[3];
    const float* b1v   = (const float*)d_in[4];
    const float* W2    = (const float*)d_in[5];
    const float* b2v   = (const float*)d_in[6];
    const float* Wc    = (const float*)d_in[7];
    const float* bc    = (const float*)d_in[8];
    const float* Wd    = (const float*)d_in[9];
    const float* bd    = (const float*)d_in[10];
    const int*   pbid  = (const int*)d_in[11];
    const int*   gbid  = (const int*)d_in[12];
    float* out = (float*)d_out;

    char* ws = (char*)d_ws;
    unsigned short* featb = (unsigned short*)(ws + FEATB_OFF);
    unsigned short* W1t   = (unsigned short*)(ws + W1T_OFF);
    unsigned short* W2t   = (unsigned short*)(ws + W2T_OFF);
    unsigned short* Wht   = (unsigned short*)(ws + WHT_OFF);
    float*          fmt   = (float*)(ws + FMT_OFF);

    k_prep<<<dim3((C_ * HID + HID * HID + 32 * HID + 255) / 256), dim3(256), 0, stream>>>(
        W1, W2, Wc, Wd, W1t, W2t, Wht);
    k_tr<<<dim3(B_ * 49 * C_ / 256), dim3(256), 0, stream>>>(fmap, fmt);
    k_pool<<<dim3(M_ * 5 / 4), dim3(256), 0, stream>>>(fmt, props, pbid, featb);
    k_fc<<<dim3(M_ / 16), dim3(256), 0, stream>>>(
        featb, W1t, W2t, Wht, b1v, b2v, bc, bd, props, pbid, bbx, gbid, out);
}